// Round 6
// baseline (509.232 us; speedup 1.0000x reference)
//
#include <hip/hip_runtime.h>
#include <stdint.h>
#include <math.h>

// Problem constants (B,T,J,D) = (64, 2048, 128, 512)
#define BB 64
#define TT 2048
#define JJ 128
#define DD 512
#define BK 32    // K chunk per step (one 16x16x32 MFMA K)

typedef short short8 __attribute__((ext_vector_type(8)));
typedef float f32x4 __attribute__((ext_vector_type(4)));

__device__ inline unsigned pk_hi(float a, float b) {
  // (hi16(a)) | (hi16(b) << 16) -- bf16 truncation pack of 2 fp32
  return __builtin_amdgcn_perm(__float_as_uint(b), __float_as_uint(a), 0x07060302u);
}
__device__ inline float truncbf(float x) {
  return __uint_as_float(__float_as_uint(x) & 0xFFFF0000u);
}
// 8 fp32 (two float4) -> hi chunk (8 bf16) + lo chunk (8 bf16)
__device__ inline void pack8(float4 a, float4 b, uint4& h, uint4& l) {
  h = make_uint4(pk_hi(a.x, a.y), pk_hi(a.z, a.w), pk_hi(b.x, b.y), pk_hi(b.z, b.w));
  float l0 = a.x - truncbf(a.x), l1 = a.y - truncbf(a.y);
  float l2 = a.z - truncbf(a.z), l3 = a.w - truncbf(a.w);
  float l4 = b.x - truncbf(b.x), l5 = b.y - truncbf(b.y);
  float l6 = b.z - truncbf(b.z), l7 = b.w - truncbf(b.w);
  l = make_uint4(pk_hi(l0, l1), pk_hi(l2, l3), pk_hi(l4, l5), pk_hi(l6, l7));
}
__device__ inline short8 bc8(uint4 u) { return __builtin_bit_cast(short8, u); }

// ================= Fully-fused kernel =======================================
// Block = (b, 16-row j-stripe). 4 waves; wave wv owns t-range [wv*512, +512).
// Each wave: acc[nt=0..31] f32x4 holds S[j = stripe*16 + q*4 + r][t = wv*512 +
// nt*16 + l15] for its range (C/D layout col=l15, row=q*4+r). Whole block thus
// holds S_stripe[16][2048] in registers -> softmax over t is block-local:
//   row-max: in-lane over nt -> shuffle over l15 (16) -> LDS over 4 waves
//   exp in place, row-sum same reduction, r = 1/s
//   out[b,t] += sum_r exp*r : butterfly over q-groups, atomicAdd by q==0 lanes
// S values are BIT-IDENTICAL to previous rounds (same 3-MFMA split scheme,
// same ks order, same fragment assignment); only fp32 sum orders differ (ULP).
// Dead work: blocks with stripe*16 >= ql retire (before any barrier); t-tile
// groups with g*64 >= cl-t0w skip loads+MFMA; t>=cl elements masked in softmax.
__global__ __launch_bounds__(256, 2)
void fused_attn(const float* __restrict__ Qm, const float* __restrict__ w,
                const float* __restrict__ Cm, const int* __restrict__ qlen,
                const int* __restrict__ clen, float* __restrict__ out) {
  // XCD-contiguous mapping: 512 blocks round-robin XCDs by id&7; remap so one
  // XCD gets 8 b's with all 8 stripes each -> C[b] streams that XCD's L2.
  const int id = blockIdx.x;
  const int nid = (id & 7) * 64 + (id >> 3);
  const int b = nid >> 3;
  const int stripe = nid & 7;

  const int ql = qlen[b];
  if (stripe * 16 >= ql) return;  // block-uniform, before any barrier
  const int cl = clen[b];

  const int tid = threadIdx.x;
  const int lane = tid & 63;
  const int wv = tid >> 6;
  const int l15 = lane & 15;
  const int q = lane >> 4;
  const int t0w = wv * 512;
  const int clw = cl - t0w;  // wave-local valid length (may be <=0)

  // A: row stripe*16 + l15, k-chunk q*8 (lane-local 32 B of Q)
  const float* qa = Qm + ((size_t)b * JJ + stripe * 16 + l15) * DD + q * 8;
  const float* wp = w + q * 8;
  // B: rows t0w + i*16 + l15 (+ g*64 per group), k-chunk q*8
  const float* cb[4];
#pragma unroll
  for (int i = 0; i < 4; i++)
    cb[i] = Cm + ((size_t)b * TT + t0w + i * 16 + l15) * DD + q * 8;

  f32x4 acc[32] = {};

#pragma unroll 1
  for (int ks = 0; ks < 16; ks++) {
    // A fragment: Q*w in fp32, split to hi/lo bf16 (bit-identical to qpack)
    const float4 w0 = *(const float4*)(wp + ks * BK);
    const float4 w1 = *(const float4*)(wp + ks * BK + 4);
    float4 a0 = *(const float4*)(qa + ks * BK);
    float4 a1 = *(const float4*)(qa + ks * BK + 4);
    a0.x *= w0.x; a0.y *= w0.y; a0.z *= w0.z; a0.w *= w0.w;
    a1.x *= w1.x; a1.y *= w1.y; a1.z *= w1.z; a1.w *= w1.w;
    uint4 h, l;
    pack8(a0, a1, h, l);
    const short8 ah = bc8(h);
    const short8 al = bc8(l);

#pragma unroll
    for (int g = 0; g < 8; g++) {
      if (g * 64 < clw) {  // wave-uniform: any valid t in this 64-t group
        float4 u0[4], u1[4];
#pragma unroll
        for (int i = 0; i < 4; i++) {
          const float* p = cb[i] + (size_t)g * (64 * DD) + ks * BK;
          u0[i] = *(const float4*)p;
          u1[i] = *(const float4*)(p + 4);
        }
#pragma unroll
        for (int i = 0; i < 4; i++) {
          uint4 bhh, bll;
          pack8(u0[i], u1[i], bhh, bll);
          const short8 bh = bc8(bhh);
          const short8 bl = bc8(bll);
          acc[g * 4 + i] = __builtin_amdgcn_mfma_f32_16x16x32_bf16(ah, bh, acc[g * 4 + i], 0, 0, 0);
          acc[g * 4 + i] = __builtin_amdgcn_mfma_f32_16x16x32_bf16(al, bh, acc[g * 4 + i], 0, 0, 0);
          acc[g * 4 + i] = __builtin_amdgcn_mfma_f32_16x16x32_bf16(ah, bl, acc[g * 4 + i], 0, 0, 0);
        }
      }
    }
  }

  // ---------------- softmax over t (block-local) ----------------
  const float NEG = -3.4e38f;
  __shared__ float mred[4][16];
  __shared__ float sred[4][16];

  // per-lane row max over this wave's t-range (masked t<cl)
  float mr[4] = {NEG, NEG, NEG, NEG};
#pragma unroll
  for (int nt = 0; nt < 32; nt++) {
    const int t = t0w + nt * 16 + l15;
    const bool v = t < cl;
#pragma unroll
    for (int r = 0; r < 4; r++) mr[r] = fmaxf(mr[r], v ? acc[nt][r] : NEG);
  }
#pragma unroll
  for (int off = 1; off < 16; off <<= 1) {
#pragma unroll
    for (int r = 0; r < 4; r++) mr[r] = fmaxf(mr[r], __shfl_xor(mr[r], off));
  }
  if (l15 == 0) {
#pragma unroll
    for (int r = 0; r < 4; r++) mred[wv][q * 4 + r] = mr[r];
  }
  __syncthreads();
#pragma unroll
  for (int r = 0; r < 4; r++) {
    mr[r] = fmaxf(fmaxf(mred[0][q * 4 + r], mred[1][q * 4 + r]),
                  fmaxf(mred[2][q * 4 + r], mred[3][q * 4 + r]));
  }

  // exp in place + per-lane row sum
  float sr[4] = {0.f, 0.f, 0.f, 0.f};
#pragma unroll
  for (int nt = 0; nt < 32; nt++) {
    const int t = t0w + nt * 16 + l15;
    const bool v = t < cl;
#pragma unroll
    for (int r = 0; r < 4; r++) {
      const float e = v ? __expf(acc[nt][r] - mr[r]) : 0.f;
      acc[nt][r] = e;
      sr[r] += e;
    }
  }
#pragma unroll
  for (int off = 1; off < 16; off <<= 1) {
#pragma unroll
    for (int r = 0; r < 4; r++) sr[r] += __shfl_xor(sr[r], off);
  }
  if (l15 == 0) {
#pragma unroll
    for (int r = 0; r < 4; r++) sred[wv][q * 4 + r] = sr[r];
  }
  __syncthreads();
  float rr[4];
#pragma unroll
  for (int r = 0; r < 4; r++) {
    const float s = sred[0][q * 4 + r] + sred[1][q * 4 + r] +
                    sred[2][q * 4 + r] + sred[3][q * 4 + r];
    rr[r] = 1.f / s;
    // rows beyond ql contribute nothing to out
    if (stripe * 16 + q * 4 + r >= ql) rr[r] = 0.f;
  }

  // ---------------- emit: out[b,t] += sum_rows exp * r ----------------
  float* ob = out + (size_t)b * TT + t0w;
#pragma unroll
  for (int nt = 0; nt < 32; nt++) {
    if (nt * 16 < clw) {  // wave-uniform; t>=cl elements hold 0
      float c = acc[nt][0] * rr[0] + acc[nt][1] * rr[1] +
                acc[nt][2] * rr[2] + acc[nt][3] * rr[3];
      c += __shfl_xor(c, 16);  // sum the 4 q-groups (16 rows total)
      c += __shfl_xor(c, 32);
      if (q == 0) atomicAdd(ob + nt * 16 + l15, c);
    }
  }
}

extern "C" void kernel_launch(void* const* d_in, const int* in_sizes, int n_in,
                              void* d_out, int out_size, void* d_ws, size_t ws_size,
                              hipStream_t stream) {
  const float* question = (const float*)d_in[0];  // (B,J,D)
  const float* context  = (const float*)d_in[1];  // (B,T,D)
  const int*   qlen     = (const int*)d_in[2];    // (B,)
  const int*   clen     = (const int*)d_in[3];    // (B,)
  const float* weight   = (const float*)d_in[4];  // (D,1)
  float* out = (float*)d_out;                     // (B,T,1) f32

  // out accumulated via atomics -> zero it first (stream-ordered, capture-safe)
  hipMemsetAsync(out, 0, (size_t)BB * TT * sizeof(float), stream);
  fused_attn<<<dim3(BB * 8), 256, 0, stream>>>(question, weight, context,
                                               qlen, clen, out);
}

// Round 9
// 398.591 us; speedup vs baseline: 1.2776x; 1.2776x over previous
//
#include <hip/hip_runtime.h>
#include <stdint.h>
#include <math.h>

// Problem constants (B,T,J,D) = (64, 2048, 128, 512)
#define BB 64
#define TT 2048
#define JJ 128
#define DD 512
#define BK 32    // K chunk per step (one 16x16x32 MFMA K)

typedef short short8 __attribute__((ext_vector_type(8)));
typedef float f32x4 __attribute__((ext_vector_type(4)));

typedef const __attribute__((address_space(1))) uint32_t glb_u32;
typedef __attribute__((address_space(3))) uint32_t lds_u32;

// async global->LDS DMA, 16B per lane; LDS dest = wave-uniform base + lane*16
__device__ __forceinline__ void dma16(const void* g, void* l) {
  __builtin_amdgcn_global_load_lds((glb_u32*)g, (lds_u32*)l, 16, 0, 0);
}

__device__ inline unsigned pk_hi(float a, float b) {
  // (hi16(a)) | (hi16(b) << 16) -- bf16 truncation pack of 2 fp32
  return __builtin_amdgcn_perm(__float_as_uint(b), __float_as_uint(a), 0x07060302u);
}
__device__ inline float truncbf(float x) {
  return __uint_as_float(__float_as_uint(x) & 0xFFFF0000u);
}
// 8 fp32 (two float4) -> hi chunk (8 bf16) + lo chunk (8 bf16)
__device__ inline void pack8(float4 a, float4 b, uint4& h, uint4& l) {
  h = make_uint4(pk_hi(a.x, a.y), pk_hi(a.z, a.w), pk_hi(b.x, b.y), pk_hi(b.z, b.w));
  float l0 = a.x - truncbf(a.x), l1 = a.y - truncbf(a.y);
  float l2 = a.z - truncbf(a.z), l3 = a.w - truncbf(a.w);
  float l4 = b.x - truncbf(b.x), l5 = b.y - truncbf(b.y);
  float l6 = b.z - truncbf(b.z), l7 = b.w - truncbf(b.w);
  l = make_uint4(pk_hi(l0, l1), pk_hi(l2, l3), pk_hi(l4, l5), pk_hi(l6, l7));
}
__device__ inline short8 bc8(uint4 u) { return __builtin_bit_cast(short8, u); }

// 16-lane butterfly reductions (rows live across l15; col group q fixed)
__device__ __forceinline__ float redmax16(float v) {
#pragma unroll
  for (int off = 1; off < 16; off <<= 1) v = fmaxf(v, __shfl_xor(v, off));
  return v;
}
__device__ __forceinline__ float redsum16(float v) {
#pragma unroll
  for (int off = 1; off < 16; off <<= 1) v += __shfl_xor(v, off);
  return v;
}

// ---------------- Kernel A0: pre-pack Q*w into hi/lo bf16 tile images --------
// Qhi/Qlo layout: [b][ks (16)][slot (512 uint4)], slot = j*4 + (c ^ ((j>>1)&3))
// i.e. exactly the byte image the GEMM wants in LDS (swizzle pre-baked).
__global__ __launch_bounds__(256)
void qpack_kernel(const float* __restrict__ Qm, const float* __restrict__ w,
                  uint4* __restrict__ Qhi, uint4* __restrict__ Qlo) {
  const int gid = blockIdx.x * 256 + threadIdx.x;  // 0 .. 524287
  const int c = gid & 3;
  const int ks = (gid >> 2) & 15;
  const int j = (gid >> 6) & 127;
  const int b = gid >> 13;
  const float* qp = Qm + (((size_t)b * JJ + j) * DD) + ks * BK + c * 8;
  const float* wp = w + ks * BK + c * 8;
  float4 a = *(const float4*)qp;
  float4 bq = *(const float4*)(qp + 4);
  float4 wa = *(const float4*)wp;
  float4 wb = *(const float4*)(wp + 4);
  a.x *= wa.x; a.y *= wa.y; a.z *= wa.z; a.w *= wa.w;
  bq.x *= wb.x; bq.y *= wb.y; bq.z *= wb.z; bq.w *= wb.w;
  uint4 h, l;
  pack8(a, bq, h, l);
  const int slot = j * 4 + (c ^ ((j >> 1) & 3));
  const size_t o = ((size_t)(b * 16 + ks)) * 512 + slot;
  Qhi[o] = h;
  Qlo[o] = l;
}

// ---------------- Kernel A: S-tile GEMM + in-register partial softmax stats --
// 128x128 tile, split-bf16 (hi/lo) 3-MFMA scheme, 16 K-steps of 32 (R2 core,
// unchanged). Epilogue: per-row (max, sum-exp) partials over this block's
// 128-t span computed from live acc registers (16-lane butterfly + 2 KB LDS
// overlay on the retired Ahi buffer), written to Part[b][tile][j]. Replaces
// the softmax_stats kernel's 17 MB S re-read.
__global__ __launch_bounds__(256, 3)
void sim_gemm_mfma(const uint4* __restrict__ Qhi, const uint4* __restrict__ Qlo,
                   const float* __restrict__ Cm, const int* __restrict__ qlen,
                   const int* __restrict__ clen, float* __restrict__ S,
                   float2* __restrict__ Part) {
  __shared__ uint4 Ahi[512];   // 8 KB : 128 rows x 4 chunks (8 bf16 each)
  __shared__ uint4 Alo[512];   // 8 KB
  __shared__ uint4 Cl[1024];   // 16 KB: 128 rows x 8 subs (4 fp32 each), swizzled

  // XCD-aware swizzle: 1024 blocks, 8 XCDs -> XCD x gets b in [x*8, x*8+8)
  const int id = blockIdx.x;
  const int nid = (id & 7) * 128 + (id >> 3);
  const int b = nid >> 4;
  const int tile = nid & 15;
  const int t0 = tile * 128;

  const int cl = clen[b];
  if (t0 >= cl) return;  // block-uniform: whole tile masked, S never read here
  const int ql = qlen[b];

  const int tid = threadIdx.x;
  const int lane = tid & 63;
  const int wv = tid >> 6;

  // ---- DMA source/dest setup (R2, unchanged)
  const uint4* qh_src = Qhi + (size_t)b * 8192 + wv * 128 + lane;
  const uint4* ql_src = Qlo + (size_t)b * 8192 + wv * 128 + lane;
  char* ah_dst = (char*)Ahi + wv * 2048;
  char* al_dst = (char*)Alo + wv * 2048;
  const int crow = wv * 32 + (lane >> 3);
  const int cch = (lane & 7) ^ ((lane >> 3) & 7);
  const float* c_src = Cm + ((size_t)b * TT + t0 + crow) * DD + cch * 4;
  char* cl_dst = (char*)Cl + wv * 4096;

  // ---- MFMA fragment assignment: 4 waves in 2x2 over 128x128
  const int wm = (wv & 1) * 64;
  const int wn = (wv >> 1) * 64;
  const int l15 = lane & 15;
  const int q = lane >> 4;
  const int fchunk = q ^ ((l15 >> 1) & 3);
  const int swl = l15 & 7;

  bool mact[4];
#pragma unroll
  for (int i = 0; i < 4; i++) mact[i] = (wm + i * 16) < ql;
  const bool any_m = mact[0];

  int aslot[4];
#pragma unroll
  for (int i = 0; i < 4; i++) aslot[i] = (wm + i * 16 + l15) * 4 + fchunk;

  f32x4 acc[4][4] = {};

  for (int ks = 0; ks < 16; ks++) {
    __syncthreads();
#pragma unroll
    for (int s = 0; s < 2; s++) {
      dma16(qh_src + ks * 512 + s * 64, ah_dst + s * 1024);
      dma16(ql_src + ks * 512 + s * 64, al_dst + s * 1024);
    }
#pragma unroll
    for (int s = 0; s < 4; s++) {
      dma16(c_src + (size_t)ks * BK + s * 8 * DD, cl_dst + s * 1024);
    }
    __syncthreads();

    if (!any_m) continue;  // compute skip only; barrier count stays uniform

    short8 bh[4], bl[4];
#pragma unroll
    for (int ni = 0; ni < 4; ni++) {
      const int row = wn + ni * 16 + l15;
      float4 v0 = __builtin_bit_cast(float4, Cl[row * 8 + ((2 * q) ^ swl)]);
      float4 v1 = __builtin_bit_cast(float4, Cl[row * 8 + ((2 * q + 1) ^ swl)]);
      uint4 h, l;
      pack8(v0, v1, h, l);
      bh[ni] = bc8(h);
      bl[ni] = bc8(l);
    }
#pragma unroll
    for (int mi = 0; mi < 4; mi++) {
      if (!mact[mi]) continue;
      short8 ah = bc8(Ahi[aslot[mi]]);
      short8 al = bc8(Alo[aslot[mi]]);
#pragma unroll
      for (int ni = 0; ni < 4; ni++) {
        acc[mi][ni] = __builtin_amdgcn_mfma_f32_16x16x32_bf16(ah, bh[ni], acc[mi][ni], 0, 0, 0);
        acc[mi][ni] = __builtin_amdgcn_mfma_f32_16x16x32_bf16(al, bh[ni], acc[mi][ni], 0, 0, 0);
        acc[mi][ni] = __builtin_amdgcn_mfma_f32_16x16x32_bf16(ah, bl[ni], acc[mi][ni], 0, 0, 0);
      }
    }
  }

  // epilogue: S store (C/D layout col=lane&15, row=(lane>>4)*4+reg)
#pragma unroll
  for (int mi = 0; mi < 4; mi++) {
    if (!mact[mi]) continue;
#pragma unroll
    for (int ni = 0; ni < 4; ni++) {
      const int j = wm + mi * 16 + q * 4;
      const int t = t0 + wn + ni * 16 + l15;
      float* dst = S + ((size_t)b * JJ + j) * TT + t;
      dst[0 * TT] = acc[mi][ni][0];
      dst[1 * TT] = acc[mi][ni][1];
      dst[2 * TT] = acc[mi][ni][2];
      dst[3 * TT] = acc[mi][ni][3];
    }
  }

  // ---- in-register partial softmax stats over this block's 128-t span ----
  // executed by ALL waves (dead-j waves write zero-acc partials into rows the
  // merge kernel never reads) -> barrier counts stay block-uniform.
  bool cv[4];
#pragma unroll
  for (int ni = 0; ni < 4; ni++) cv[ni] = (t0 + wn + ni * 16 + l15) < cl;

  const float NEG = -3.4e38f;
  __syncthreads();  // all waves past their last Ahi/Alo reads
  float* Pm = (float*)Ahi;        // overlay: [128 rows][2 halves]
  float* Ps = Pm + 256;           // overlay: [128 rows][2 halves]
  const int half = wv >> 1;       // wn==0 -> 0, wn==64 -> 1

  // half-row max over this wave's 64 cols; rows = wm + mi*16 + q*4 + r
  float mrow[4][4];
#pragma unroll
  for (int mi = 0; mi < 4; mi++) {
#pragma unroll
    for (int r = 0; r < 4; r++) {
      float m = NEG;
#pragma unroll
      for (int ni = 0; ni < 4; ni++) m = fmaxf(m, cv[ni] ? acc[mi][ni][r] : NEG);
      mrow[mi][r] = redmax16(m);
    }
  }
  if (l15 == 0) {
#pragma unroll
    for (int mi = 0; mi < 4; mi++)
#pragma unroll
      for (int r = 0; r < 4; r++)
        Pm[(wm + mi * 16 + q * 4 + r) * 2 + half] = mrow[mi][r];
  }
  __syncthreads();
  // full row max (both t-halves) -> sum exp(S - m) over this wave's cols
  float srow[4][4];
#pragma unroll
  for (int mi = 0; mi < 4; mi++) {
#pragma unroll
    for (int r = 0; r < 4; r++) {
      const int row = wm + mi * 16 + q * 4 + r;
      const float mf = fmaxf(Pm[row * 2 + 0], Pm[row * 2 + 1]);
      float s = 0.f;
#pragma unroll
      for (int ni = 0; ni < 4; ni++)
        s += cv[ni] ? __expf(acc[mi][ni][r] - mf) : 0.f;
      srow[mi][r] = redsum16(s);
    }
  }
  if (l15 == 0) {
#pragma unroll
    for (int mi = 0; mi < 4; mi++)
#pragma unroll
      for (int r = 0; r < 4; r++)
        Ps[(wm + mi * 16 + q * 4 + r) * 2 + half] = srow[mi][r];
  }
  __syncthreads();
  // one thread per row writes the (max, sumexp) partial for this tile
  if (tid < JJ) {
    const float m = fmaxf(Pm[tid * 2 + 0], Pm[tid * 2 + 1]);
    const float s = Ps[tid * 2 + 0] + Ps[tid * 2 + 1];
    Part[((size_t)b * 16 + tile) * JJ + tid] = make_float2(m, s);
  }
}

// ---------------- Kernel B: merge per-tile partials -> m, r=1/s -------------
// Online merge over the <=16 alive tiles of each (b,j) row. Max is exact;
// sumexp differs from direct summation only in fp32 order (~1 ulp on r).
__global__ __launch_bounds__(256)
void merge_kernel(const float2* __restrict__ Part, const int* __restrict__ qlen,
                  const int* __restrict__ clen, float* __restrict__ m_out,
                  float* __restrict__ r_out) {
  const int gid = blockIdx.x * 256 + threadIdx.x;  // 0 .. 8191
  const int b = gid >> 7;
  const int j = gid & 127;
  if (j >= qlen[b]) return;
  const int nt = (clen[b] + 127) >> 7;  // alive tiles (all wrote Part)
  float m = -3.4e38f;
  float s = 0.f;
  for (int i = 0; i < nt; i++) {
    const float2 p = Part[((size_t)b * 16 + i) * JJ + j];
    if (p.x > m) {
      s = s * __expf(m - p.x) + p.y;
      m = p.x;
    } else {
      s += p.y * __expf(p.x - m);
    }
  }
  m_out[(size_t)b * JJ + j] = m;
  r_out[(size_t)b * JJ + j] = 1.f / s;
}

// ---------------- Kernel C: out[b,t] = sum_{j<qlen} exp(S-m)*r ---------------
__global__ __launch_bounds__(256)
void out_kernel(const float* __restrict__ S, const float* __restrict__ m_arr,
                const float* __restrict__ r_arr, const int* __restrict__ qlen,
                const int* __restrict__ clen, float* __restrict__ out) {
  const int b = blockIdx.y;
  const int t = blockIdx.x * 256 + threadIdx.x;
  const int ql = qlen[b];
  const int cl = clen[b];

  __shared__ float lm[JJ];
  __shared__ float lr[JJ];
  if (threadIdx.x < ql) {
    lm[threadIdx.x] = m_arr[(size_t)b * JJ + threadIdx.x];
    lr[threadIdx.x] = r_arr[(size_t)b * JJ + threadIdx.x];
  }
  __syncthreads();

  float acc = 0.f;
  if (t < cl) {
    const float* col = S + (size_t)b * JJ * TT + t;
#pragma unroll 4
    for (int j = 0; j < ql; j++) {
      acc += __expf(col[(size_t)j * TT] - lm[j]) * lr[j];
    }
  }
  out[(size_t)b * TT + t] = acc;
}

extern "C" void kernel_launch(void* const* d_in, const int* in_sizes, int n_in,
                              void* d_out, int out_size, void* d_ws, size_t ws_size,
                              hipStream_t stream) {
  const float* question = (const float*)d_in[0];  // (B,J,D)
  const float* context  = (const float*)d_in[1];  // (B,T,D)
  const int*   qlen     = (const int*)d_in[2];    // (B,)
  const int*   clen     = (const int*)d_in[3];    // (B,)
  const float* weight   = (const float*)d_in[4];  // (D,1)
  float* out = (float*)d_out;                     // (B,T,1) f32

  // Workspace: S (64 MB) + m + r + Qhi (8 MB) + Qlo (8 MB) + Part (1 MB)
  float* S = (float*)d_ws;
  float* m_arr = S + (size_t)BB * JJ * TT;
  float* r_arr = m_arr + (size_t)BB * JJ;
  uint4* Qhi = (uint4*)(r_arr + (size_t)BB * JJ);
  uint4* Qlo = Qhi + (size_t)BB * 16 * 512;
  float2* Part = (float2*)(Qlo + (size_t)BB * 16 * 512);

  qpack_kernel<<<dim3(2048), 256, 0, stream>>>(question, weight, Qhi, Qlo);
  sim_gemm_mfma<<<dim3(1024), 256, 0, stream>>>(Qhi, Qlo, context, qlen, clen, S, Part);
  merge_kernel<<<dim3(32), 256, 0, stream>>>(Part, qlen, clen, m_arr, r_arr);
  out_kernel<<<dim3(TT / 256, BB), 256, 0, stream>>>(S, m_arr, r_arr, qlen, clen, out);
}